// Round 1
// baseline (513.918 us; speedup 1.0000x reference)
//
#include <hip/hip_runtime.h>
#include <hip/hip_bf16.h>

#define DIM 2048
#define NH 32
#define NKV 8
#define HD 64
#define SEQ 2048
#define BATCH 2
#define MTOT (BATCH*SEQ)          // 4096
#define QKV_N ((NH + 2*NKV)*HD)   // 3072

typedef __bf16 bf16x8 __attribute__((ext_vector_type(8)));
typedef float f32x4 __attribute__((ext_vector_type(4)));

__device__ __forceinline__ void gld_lds16(const void* g, void* l) {
  __builtin_amdgcn_global_load_lds((__attribute__((address_space(1))) void*)g,
                                   (__attribute__((address_space(3))) void*)l,
                                   16, 0, 0);
}

// ---------------- elementwise: fp32 -> bf16 ----------------
__global__ void cvt_x_kernel(const float* __restrict__ src, __hip_bfloat16* __restrict__ dst, int n4) {
  int i = blockIdx.x * 256 + threadIdx.x;
  if (i >= n4) return;
  float4 v = ((const float4*)src)[i];
  union { __hip_bfloat16 h[4]; uint2 u; } t;
  t.h[0] = __float2bfloat16(v.x); t.h[1] = __float2bfloat16(v.y);
  t.h[2] = __float2bfloat16(v.z); t.h[3] = __float2bfloat16(v.w);
  ((uint2*)dst)[i] = t.u;
}

// ---------------- transpose + convert: src R x C fp32 -> dst C x R bf16 ----------------
__global__ void transpose_cvt_kernel(const float* __restrict__ src, __hip_bfloat16* __restrict__ dst,
                                     int R, int C) {
  __shared__ float tile[32][33];
  int c0 = blockIdx.x * 32, r0 = blockIdx.y * 32;
  int tx = threadIdx.x & 31, ty = threadIdx.x >> 5;   // 256 threads: ty in 0..7
  #pragma unroll
  for (int i = ty; i < 32; i += 8)
    tile[i][tx] = src[(size_t)(r0 + i) * C + c0 + tx];
  __syncthreads();
  #pragma unroll
  for (int i = ty; i < 32; i += 8)
    dst[(size_t)(c0 + i) * R + r0 + tx] = __float2bfloat16(tile[tx][i]);
}

// ---------------- RoPE + scatter to head-major Q/K/V (bf16) ----------------
// qkv: [MTOT][3072] bf16 (cols 0..2047 q, 2048..2559 k, 2560..3071 v)
// Q: [B][NH][S][64], K/V: [B][NKV][S][64]
__global__ void rope_scatter_kernel(const __hip_bfloat16* __restrict__ qkv,
                                    const float* __restrict__ freqs,
                                    __hip_bfloat16* __restrict__ Q,
                                    __hip_bfloat16* __restrict__ K,
                                    __hip_bfloat16* __restrict__ V) {
  int row = blockIdx.y;                      // b*SEQ + s
  int c   = blockIdx.x * 256 + threadIdx.x;  // 0..1535 (pair index)
  int b = row >> 11, s = row & 2047;
  const __hip_bfloat16* qr = qkv + (size_t)row * QKV_N;
  if (c < 1024) {            // q pairs
    int h = c >> 5, i = c & 31;
    float x0 = __bfloat162float(qr[h * 64 + 2 * i]);
    float x1 = __bfloat162float(qr[h * 64 + 2 * i + 1]);
    float f0 = freqs[s * 64 + 2 * i], f1 = freqs[s * 64 + 2 * i + 1];
    size_t o = ((size_t)(b * NH + h) * SEQ + s) * HD + 2 * i;
    Q[o]     = __float2bfloat16(x0 * f0 - x1 * f1);
    Q[o + 1] = __float2bfloat16(x1 * f0 + x0 * f1);
  } else if (c < 1280) {     // k pairs
    int cc = c - 1024, kh = cc >> 5, i = cc & 31;
    float x0 = __bfloat162float(qr[2048 + kh * 64 + 2 * i]);
    float x1 = __bfloat162float(qr[2048 + kh * 64 + 2 * i + 1]);
    float f0 = freqs[s * 64 + 2 * i], f1 = freqs[s * 64 + 2 * i + 1];
    size_t o = ((size_t)(b * NKV + kh) * SEQ + s) * HD + 2 * i;
    K[o]     = __float2bfloat16(x0 * f0 - x1 * f1);
    K[o + 1] = __float2bfloat16(x1 * f0 + x0 * f1);
  } else {                   // v copy
    int cc = c - 1280, vh = cc >> 5, i = cc & 31;
    size_t o = ((size_t)(b * NKV + vh) * SEQ + s) * HD + 2 * i;
    V[o]     = qr[2560 + vh * 64 + 2 * i];
    V[o + 1] = qr[2560 + vh * 64 + 2 * i + 1];
  }
}

// ---------------- bf16 MFMA GEMM: C[M][N] = A[M][K] * Bt[N][K]^T ----------------
// m97 structure: 128x128 tile, BK=32, 4 waves (2x2 of 64x64), global_load_lds w=16.
__device__ __forceinline__ void store_val(float* p, float v) { *p = v; }
__device__ __forceinline__ void store_val(__hip_bfloat16* p, float v) { *p = __float2bfloat16(v); }

template <typename OutT>
__global__ __launch_bounds__(256) void gemm_bt_kernel(const __hip_bfloat16* __restrict__ A,
                                                      const __hip_bfloat16* __restrict__ Bt,
                                                      OutT* __restrict__ C, int M, int N, int K) {
  __shared__ __hip_bfloat16 As[128 * 32];   // [row][k], unpadded (global_load_lds constraint)
  __shared__ __hip_bfloat16 Bs[128 * 32];   // [n][k]
  const int tid = threadIdx.x;
  const int w = tid >> 6, lane = tid & 63, ln = lane & 15, quad = lane >> 4;
  const int m0 = blockIdx.y * 128, n0 = blockIdx.x * 128;
  const int wm = (w >> 1) * 64, wn = (w & 1) * 64;
  // staging: wave w covers LDS bytes [w*1024, w*1024+1024); lane l -> base + l*16
  const int srow = w * 16 + (lane >> 2), scol = (lane & 3) * 8;
  const __hip_bfloat16* Ag = A + (size_t)(m0 + srow) * K + scol;
  const __hip_bfloat16* Bg = Bt + (size_t)(n0 + srow) * K + scol;
  __hip_bfloat16* AsW = &As[w * 512];
  __hip_bfloat16* BsW = &Bs[w * 512];
  f32x4 acc[4][4] = {};
  for (int k0 = 0; k0 < K; k0 += 32) {
    gld_lds16(Ag + k0, AsW);
    gld_lds16(Ag + 64 * (size_t)K + k0, AsW + 2048);
    gld_lds16(Bg + k0, BsW);
    gld_lds16(Bg + 64 * (size_t)K + k0, BsW + 2048);
    __syncthreads();
    bf16x8 af[4], bf[4];
    #pragma unroll
    for (int i = 0; i < 4; i++)
      af[i] = *(const bf16x8*)&As[(wm + i * 16 + ln) * 32 + quad * 8];
    #pragma unroll
    for (int j = 0; j < 4; j++)
      bf[j] = *(const bf16x8*)&Bs[(wn + j * 16 + ln) * 32 + quad * 8];
    #pragma unroll
    for (int i = 0; i < 4; i++)
      #pragma unroll
      for (int j = 0; j < 4; j++)
        acc[i][j] = __builtin_amdgcn_mfma_f32_16x16x32_bf16(af[i], bf[j], acc[i][j], 0, 0, 0);
    __syncthreads();
  }
  // epilogue: C-frag element (reg r): row = quad*4+r, col = ln
  #pragma unroll
  for (int i = 0; i < 4; i++) {
    const int r0 = m0 + wm + i * 16 + quad * 4;
    #pragma unroll
    for (int j = 0; j < 4; j++) {
      const int cc = n0 + wn + j * 16 + ln;
      #pragma unroll
      for (int r = 0; r < 4; r++)
        store_val(&C[(size_t)(r0 + r) * N + cc], acc[i][j][r]);
    }
  }
}

// ---------------- flash-style causal GQA attention ----------------
// grid (S/64, NH, B); 4 waves, wave w owns q rows [qt*64 + w*16, +16)
__global__ __launch_bounds__(256) void attn_kernel(const __hip_bfloat16* __restrict__ Q,
                                                   const __hip_bfloat16* __restrict__ Kg,
                                                   const __hip_bfloat16* __restrict__ Vg,
                                                   __hip_bfloat16* __restrict__ O) {
  __shared__ __hip_bfloat16 Ks[64 * 72];      // [s_kv][d], padded stride 72
  __shared__ __hip_bfloat16 Vs[64 * 72];      // transposed: [d][s_kv]
  __shared__ __hip_bfloat16 Ps[4][16 * 72];   // per-wave P scratch [qrow][s_kv]
  const int qt = blockIdx.x, h = blockIdx.y, b = blockIdx.z;
  const int kvh = h >> 2;
  const int tid = threadIdx.x, w = tid >> 6, lane = tid & 63, ln = lane & 15, quad = lane >> 4;
  const size_t qbase = (size_t)(b * NH + h) * SEQ * HD;
  const size_t kbase = (size_t)(b * NKV + kvh) * SEQ * HD;
  // Q fragments (A-layout: m=ln, k=quad*8+j, kt selects k half)
  bf16x8 qf[2];
  const int qrow = qt * 64 + w * 16 + ln;
  #pragma unroll
  for (int kt = 0; kt < 2; kt++)
    qf[kt] = *(const bf16x8*)(Q + qbase + (size_t)qrow * HD + kt * 32 + quad * 8);
  f32x4 Oacc[4] = {};
  float mrow[4] = {-INFINITY, -INFINITY, -INFINITY, -INFINITY};
  float lrow[4] = {};
  for (int j = 0; j <= qt; j++) {
    // stage K tile (row-major) and V tile (transposed)
    #pragma unroll
    for (int cc = 0; cc < 2; cc++) {
      int c = tid * 2 + cc;
      int row = c >> 3, off = (c & 7) * 8;
      uint4 kd = *(const uint4*)(Kg + kbase + (size_t)(j * 64 + row) * HD + off);
      *(uint4*)&Ks[row * 72 + off] = kd;
      uint4 vd = *(const uint4*)(Vg + kbase + (size_t)(j * 64 + row) * HD + off);
      const __hip_bfloat16* vp = (const __hip_bfloat16*)&vd;
      #pragma unroll
      for (int e = 0; e < 8; e++)
        Vs[(off + e) * 72 + row] = vp[e];
    }
    __syncthreads();
    // S = Q K^T for this wave's 16 rows x 64 kv cols
    f32x4 sf[4];
    #pragma unroll
    for (int nt = 0; nt < 4; nt++) {
      f32x4 s = {};
      #pragma unroll
      for (int kt = 0; kt < 2; kt++) {
        bf16x8 kf = *(const bf16x8*)&Ks[(nt * 16 + ln) * 72 + kt * 32 + quad * 8];
        s = __builtin_amdgcn_mfma_f32_16x16x32_bf16(qf[kt], kf, s, 0, 0, 0);
      }
      sf[nt] = s;
    }
    // scale + causal mask (C-layout: row = quad*4+r, col = nt*16+ln)
    const int qg = qt * 64 + w * 16 + quad * 4;
    #pragma unroll
    for (int nt = 0; nt < 4; nt++) {
      const int kg = j * 64 + nt * 16 + ln;
      #pragma unroll
      for (int r = 0; r < 4; r++) {
        float v = sf[nt][r] * 0.125f;
        sf[nt][r] = (kg <= qg + r) ? v : -INFINITY;
      }
    }
    // online softmax: row max (reduce over 16 lanes of the quad group)
    float alpha[4];
    #pragma unroll
    for (int r = 0; r < 4; r++) {
      float v = fmaxf(fmaxf(sf[0][r], sf[1][r]), fmaxf(sf[2][r], sf[3][r]));
      #pragma unroll
      for (int off = 1; off < 16; off <<= 1)
        v = fmaxf(v, __shfl_xor(v, off, 16));
      float mn = fmaxf(mrow[r], v);
      alpha[r] = __expf(mrow[r] - mn);
      mrow[r] = mn;
    }
    // P = exp(S - m), row sums
    #pragma unroll
    for (int r = 0; r < 4; r++) {
      float rs = 0.f;
      #pragma unroll
      for (int nt = 0; nt < 4; nt++) {
        float p = __expf(sf[nt][r] - mrow[r]);
        sf[nt][r] = p;
        rs += p;
      }
      #pragma unroll
      for (int off = 1; off < 16; off <<= 1)
        rs += __shfl_xor(rs, off, 16);
      lrow[r] = lrow[r] * alpha[r] + rs;
    }
    // P: C-layout -> LDS -> A-layout (per-wave scratch, no barrier needed)
    #pragma unroll
    for (int nt = 0; nt < 4; nt++)
      #pragma unroll
      for (int r = 0; r < 4; r++)
        Ps[w][(quad * 4 + r) * 72 + nt * 16 + ln] = __float2bfloat16(sf[nt][r]);
    #pragma unroll
    for (int dt = 0; dt < 4; dt++)
      #pragma unroll
      for (int r = 0; r < 4; r++)
        Oacc[dt][r] *= alpha[r];
    bf16x8 pf[2];
    #pragma unroll
    for (int kt = 0; kt < 2; kt++)
      pf[kt] = *(const bf16x8*)&Ps[w][ln * 72 + kt * 32 + quad * 8];
    #pragma unroll
    for (int dt = 0; dt < 4; dt++) {
      #pragma unroll
      for (int kt = 0; kt < 2; kt++) {
        bf16x8 vf = *(const bf16x8*)&Vs[(dt * 16 + ln) * 72 + kt * 32 + quad * 8];
        Oacc[dt] = __builtin_amdgcn_mfma_f32_16x16x32_bf16(pf[kt], vf, Oacc[dt], 0, 0, 0);
      }
    }
    __syncthreads();
  }
  // epilogue: out[b][s][h*64+d], divide by l
  const int so = qt * 64 + w * 16 + quad * 4;
  #pragma unroll
  for (int dt = 0; dt < 4; dt++)
    #pragma unroll
    for (int r = 0; r < 4; r++)
      O[((size_t)(b * SEQ) + so + r) * DIM + h * HD + dt * 16 + ln] =
          __float2bfloat16(Oacc[dt][r] / lrow[r]);
}

extern "C" void kernel_launch(void* const* d_in, const int* in_sizes, int n_in,
                              void* d_out, int out_size, void* d_ws, size_t ws_size,
                              hipStream_t stream) {
  const float* x     = (const float*)d_in[0];
  const float* freqs = (const float*)d_in[1];
  const float* wqkv  = (const float*)d_in[2];
  const float* wo    = (const float*)d_in[3];
  float* out = (float*)d_out;

  char* ws = (char*)d_ws;
  __hip_bfloat16* xb    = (__hip_bfloat16*)ws; ws += (size_t)MTOT * DIM * 2;
  __hip_bfloat16* wqkvT = (__hip_bfloat16*)ws; ws += (size_t)QKV_N * DIM * 2;
  __hip_bfloat16* woT   = (__hip_bfloat16*)ws; ws += (size_t)DIM * DIM * 2;
  __hip_bfloat16* qkvb  = (__hip_bfloat16*)ws; ws += (size_t)MTOT * QKV_N * 2;
  __hip_bfloat16* Qb    = (__hip_bfloat16*)ws; ws += (size_t)BATCH * NH * SEQ * HD * 2;
  __hip_bfloat16* Kb    = (__hip_bfloat16*)ws; ws += (size_t)BATCH * NKV * SEQ * HD * 2;
  __hip_bfloat16* Vb    = (__hip_bfloat16*)ws; ws += (size_t)BATCH * NKV * SEQ * HD * 2;
  __hip_bfloat16* attn  = (__hip_bfloat16*)ws; ws += (size_t)MTOT * DIM * 2;
  // total ws used: ~100 MB

  cvt_x_kernel<<<(MTOT * DIM / 4 + 255) / 256, 256, 0, stream>>>(x, xb, MTOT * DIM / 4);
  transpose_cvt_kernel<<<dim3(QKV_N / 32, DIM / 32), 256, 0, stream>>>(wqkv, wqkvT, DIM, QKV_N);
  transpose_cvt_kernel<<<dim3(DIM / 32, DIM / 32), 256, 0, stream>>>(wo, woT, DIM, DIM);
  gemm_bt_kernel<__hip_bfloat16><<<dim3(QKV_N / 128, MTOT / 128), 256, 0, stream>>>(
      xb, wqkvT, qkvb, MTOT, QKV_N, DIM);
  rope_scatter_kernel<<<dim3(6, MTOT), 256, 0, stream>>>(qkvb, freqs, Qb, Kb, Vb);
  attn_kernel<<<dim3(SEQ / 64, NH, BATCH), 256, 0, stream>>>(Qb, Kb, Vb, attn);
  gemm_bt_kernel<float><<<dim3(DIM / 128, MTOT / 128), 256, 0, stream>>>(
      attn, woT, out, MTOT, DIM, DIM);
}

// Round 2
// 389.561 us; speedup vs baseline: 1.3192x; 1.3192x over previous
//
#include <hip/hip_runtime.h>
#include <hip/hip_bf16.h>

#define DIM 2048
#define NH 32
#define NKV 8
#define HD 64
#define SEQ 2048
#define BATCH 2
#define MTOT (BATCH*SEQ)          // 4096
#define QKV_N ((NH + 2*NKV)*HD)   // 3072

typedef __bf16 bf16x8 __attribute__((ext_vector_type(8)));
typedef float f32x4 __attribute__((ext_vector_type(4)));

__device__ __forceinline__ void gld_lds16(const void* g, void* l) {
  __builtin_amdgcn_global_load_lds((__attribute__((address_space(1))) void*)g,
                                   (__attribute__((address_space(3))) void*)l,
                                   16, 0, 0);
}

// ---------------- elementwise: fp32 -> bf16 ----------------
__global__ void cvt_x_kernel(const float* __restrict__ src, __hip_bfloat16* __restrict__ dst, int n4) {
  int i = blockIdx.x * 256 + threadIdx.x;
  if (i >= n4) return;
  float4 v = ((const float4*)src)[i];
  union { __hip_bfloat16 h[4]; uint2 u; } t;
  t.h[0] = __float2bfloat16(v.x); t.h[1] = __float2bfloat16(v.y);
  t.h[2] = __float2bfloat16(v.z); t.h[3] = __float2bfloat16(v.w);
  ((uint2*)dst)[i] = t.u;
}

// ---------------- transpose + convert: src R x C fp32 -> dst C x R bf16 ----------------
__global__ void transpose_cvt_kernel(const float* __restrict__ src, __hip_bfloat16* __restrict__ dst,
                                     int R, int C) {
  __shared__ float tile[32][33];
  int c0 = blockIdx.x * 32, r0 = blockIdx.y * 32;
  int tx = threadIdx.x & 31, ty = threadIdx.x >> 5;
  #pragma unroll
  for (int i = ty; i < 32; i += 8)
    tile[i][tx] = src[(size_t)(r0 + i) * C + c0 + tx];
  __syncthreads();
  #pragma unroll
  for (int i = ty; i < 32; i += 8)
    dst[(size_t)(c0 + i) * R + r0 + tx] = __float2bfloat16(tile[tx][i]);
}

// ---------------- RoPE + scatter to head-major Q/K/V (bf16) ----------------
__global__ void rope_scatter_kernel(const __hip_bfloat16* __restrict__ qkv,
                                    const float* __restrict__ freqs,
                                    __hip_bfloat16* __restrict__ Q,
                                    __hip_bfloat16* __restrict__ K,
                                    __hip_bfloat16* __restrict__ V) {
  int row = blockIdx.y;                      // b*SEQ + s
  int c   = blockIdx.x * 256 + threadIdx.x;  // 0..1535 (pair index)
  int b = row >> 11, s = row & 2047;
  const __hip_bfloat16* qr = qkv + (size_t)row * QKV_N;
  if (c < 1024) {            // q pairs
    int h = c >> 5, i = c & 31;
    float x0 = __bfloat162float(qr[h * 64 + 2 * i]);
    float x1 = __bfloat162float(qr[h * 64 + 2 * i + 1]);
    float f0 = freqs[s * 64 + 2 * i], f1 = freqs[s * 64 + 2 * i + 1];
    size_t o = ((size_t)(b * NH + h) * SEQ + s) * HD + 2 * i;
    Q[o]     = __float2bfloat16(x0 * f0 - x1 * f1);
    Q[o + 1] = __float2bfloat16(x1 * f0 + x0 * f1);
  } else if (c < 1280) {     // k pairs
    int cc = c - 1024, kh = cc >> 5, i = cc & 31;
    float x0 = __bfloat162float(qr[2048 + kh * 64 + 2 * i]);
    float x1 = __bfloat162float(qr[2048 + kh * 64 + 2 * i + 1]);
    float f0 = freqs[s * 64 + 2 * i], f1 = freqs[s * 64 + 2 * i + 1];
    size_t o = ((size_t)(b * NKV + kh) * SEQ + s) * HD + 2 * i;
    K[o]     = __float2bfloat16(x0 * f0 - x1 * f1);
    K[o + 1] = __float2bfloat16(x1 * f0 + x0 * f1);
  } else {                   // v copy
    int cc = c - 1280, vh = cc >> 5, i = cc & 31;
    size_t o = ((size_t)(b * NKV + vh) * SEQ + s) * HD + 2 * i;
    V[o]     = qr[2560 + vh * 64 + 2 * i];
    V[o + 1] = qr[2560 + vh * 64 + 2 * i + 1];
  }
}

// ---------------- bf16 MFMA GEMM: C[M][N] = A[M][K] * Bt[N][K]^T ----------------
__device__ __forceinline__ void store_val(float* p, float v) { *p = v; }
__device__ __forceinline__ void store_val(__hip_bfloat16* p, float v) { *p = __float2bfloat16(v); }

template <typename OutT>
__global__ __launch_bounds__(256) void gemm_bt_kernel(const __hip_bfloat16* __restrict__ A,
                                                      const __hip_bfloat16* __restrict__ Bt,
                                                      OutT* __restrict__ C, int M, int N, int K) {
  __shared__ __hip_bfloat16 As[128 * 32];
  __shared__ __hip_bfloat16 Bs[128 * 32];
  const int tid = threadIdx.x;
  const int w = tid >> 6, lane = tid & 63, ln = lane & 15, quad = lane >> 4;
  const int m0 = blockIdx.y * 128, n0 = blockIdx.x * 128;
  const int wm = (w >> 1) * 64, wn = (w & 1) * 64;
  const int srow = w * 16 + (lane >> 2), scol = (lane & 3) * 8;
  const __hip_bfloat16* Ag = A + (size_t)(m0 + srow) * K + scol;
  const __hip_bfloat16* Bg = Bt + (size_t)(n0 + srow) * K + scol;
  __hip_bfloat16* AsW = &As[w * 512];
  __hip_bfloat16* BsW = &Bs[w * 512];
  f32x4 acc[4][4] = {};
  for (int k0 = 0; k0 < K; k0 += 32) {
    gld_lds16(Ag + k0, AsW);
    gld_lds16(Ag + 64 * (size_t)K + k0, AsW + 2048);
    gld_lds16(Bg + k0, BsW);
    gld_lds16(Bg + 64 * (size_t)K + k0, BsW + 2048);
    __syncthreads();
    bf16x8 af[4], bf[4];
    #pragma unroll
    for (int i = 0; i < 4; i++)
      af[i] = *(const bf16x8*)&As[(wm + i * 16 + ln) * 32 + quad * 8];
    #pragma unroll
    for (int j = 0; j < 4; j++)
      bf[j] = *(const bf16x8*)&Bs[(wn + j * 16 + ln) * 32 + quad * 8];
    #pragma unroll
    for (int i = 0; i < 4; i++)
      #pragma unroll
      for (int j = 0; j < 4; j++)
        acc[i][j] = __builtin_amdgcn_mfma_f32_16x16x32_bf16(af[i], bf[j], acc[i][j], 0, 0, 0);
    __syncthreads();
  }
  #pragma unroll
  for (int i = 0; i < 4; i++) {
    const int r0 = m0 + wm + i * 16 + quad * 4;
    #pragma unroll
    for (int j = 0; j < 4; j++) {
      const int cc = n0 + wn + j * 16 + ln;
      #pragma unroll
      for (int r = 0; r < 4; r++)
        store_val(&C[(size_t)(r0 + r) * N + cc], acc[i][j][r]);
    }
  }
}

// ---------------- flash-style causal GQA attention, balanced + conflict-free ----------------
// grid (8 pairs, NH, B); block handles q-tiles {p, 15-p} of 128 rows each.
// 4 waves x 32 q-rows; KV tile 64. Every block does exactly 34 KV-iterations.
__global__ __launch_bounds__(256) void attn_kernel(const __hip_bfloat16* __restrict__ Q,
                                                   const __hip_bfloat16* __restrict__ Kg,
                                                   const __hip_bfloat16* __restrict__ Vg,
                                                   __hip_bfloat16* __restrict__ O) {
  __shared__ __hip_bfloat16 Ks[64 * 72];      // [kv][d], stride 72
  __shared__ __hip_bfloat16 Vs[64 * 72];      // [d][kv^swz(d)], swz(d)=((d>>4)&3)*16
  __shared__ __hip_bfloat16 Ps[4][32 * 72];   // per-wave P [row][col^swz(row)], swz(row)=((row>>2)&3)*16
  const int p = blockIdx.x, h = blockIdx.y, b = blockIdx.z;
  const int kvh = h >> 2;
  const int tid = threadIdx.x, w = tid >> 6, lane = tid & 63, ln = lane & 15, quad = lane >> 4;
  const size_t qbase = (size_t)(b * NH + h) * SEQ * HD;
  const size_t kbase = (size_t)(b * NKV + kvh) * SEQ * HD;
  // staging map: thread -> (row 0..63, col group); per-wave rows span w*16..w*16+15,
  // V-store banks = e*4 + (w^(lane&3))*8 + (lane>>3) -> all 32 banks, 2-way (free).
  const int srow = tid >> 2;
  const int scb  = (tid & 3) * 16;
  const int vsw  = (tid & 3) << 4;   // = ((d>>4)&3)*16 for this thread's d range
  union { unsigned short u[8]; bf16x8 v; } onesu;
  #pragma unroll
  for (int i = 0; i < 8; i++) onesu.u[i] = 0x3F80;  // bf16 1.0
  const bf16x8 ones = onesu.v;
  const int psw = ((ln >> 2) & 3) << 4;  // Ps read swizzle for row=ln

  for (int half = 0; half < 2; half++) {
    const int t = half ? (15 - p) : p;
    const int qb = t << 7;             // q-tile base row
    const int qgw = qb + w * 32;       // this wave's first q row
    bf16x8 qf[2][2];
    #pragma unroll
    for (int f = 0; f < 2; f++)
      #pragma unroll
      for (int kt = 0; kt < 2; kt++)
        qf[f][kt] = *(const bf16x8*)(Q + qbase + (size_t)(qgw + f * 16 + ln) * HD + kt * 32 + quad * 8);
    f32x4 Oacc[2][4] = {};
    float mrow[2][4], lrow[2][4];
    #pragma unroll
    for (int f = 0; f < 2; f++)
      #pragma unroll
      for (int r = 0; r < 4; r++) { mrow[f][r] = -INFINITY; lrow[f][r] = 0.f; }
    const int nkv = (qb >> 6) + 2;
    const int jmaxw = (qgw + 31) >> 6;
    // prefetch tile 0
    uint4 kd[2], vd[2];
    #pragma unroll
    for (int cc = 0; cc < 2; cc++) {
      const size_t g = kbase + (size_t)srow * HD + scb + cc * 8;
      kd[cc] = *(const uint4*)(Kg + g);
      vd[cc] = *(const uint4*)(Vg + g);
    }
    for (int j = 0; j < nkv; j++) {
      // write staged regs to LDS
      #pragma unroll
      for (int cc = 0; cc < 2; cc++) {
        const int col = scb + cc * 8;
        *(uint4*)&Ks[srow * 72 + col] = kd[cc];
        const __hip_bfloat16* vp = (const __hip_bfloat16*)&vd[cc];
        #pragma unroll
        for (int e = 0; e < 8; e++)
          Vs[(col + e) * 72 + (srow ^ vsw)] = vp[e];
      }
      __syncthreads();
      // prefetch next tile (overlaps compute)
      if (j + 1 < nkv) {
        #pragma unroll
        for (int cc = 0; cc < 2; cc++) {
          const size_t g = kbase + (size_t)((j + 1) * 64 + srow) * HD + scb + cc * 8;
          kd[cc] = *(const uint4*)(Kg + g);
          vd[cc] = *(const uint4*)(Vg + g);
        }
      }
      if (j <= jmaxw) {
        // S = Q K^T : 16 MFMAs
        bf16x8 kf[4][2];
        #pragma unroll
        for (int nt = 0; nt < 4; nt++)
          #pragma unroll
          for (int kt = 0; kt < 2; kt++)
            kf[nt][kt] = *(const bf16x8*)&Ks[(nt * 16 + ln) * 72 + kt * 32 + quad * 8];
        f32x4 sf[2][4];
        #pragma unroll
        for (int f = 0; f < 2; f++)
          #pragma unroll
          for (int nt = 0; nt < 4; nt++) {
            f32x4 s = {};
            #pragma unroll
            for (int kt = 0; kt < 2; kt++)
              s = __builtin_amdgcn_mfma_f32_16x16x32_bf16(qf[f][kt], kf[nt][kt], s, 0, 0, 0);
            sf[f][nt] = s;
          }
        // softmax per fragment
        #pragma unroll
        for (int f = 0; f < 2; f++) {
          const bool needMask = (j * 64 + 63) > (qgw + f * 16);
          #pragma unroll
          for (int nt = 0; nt < 4; nt++) {
            const int kg = j * 64 + nt * 16 + ln;
            #pragma unroll
            for (int r = 0; r < 4; r++) {
              float v = sf[f][nt][r] * 0.125f;
              if (needMask) v = (kg <= qgw + f * 16 + quad * 4 + r) ? v : -3.0e38f;
              sf[f][nt][r] = v;
            }
          }
          float alpha[4];
          #pragma unroll
          for (int r = 0; r < 4; r++) {
            float v = fmaxf(fmaxf(sf[f][0][r], sf[f][1][r]), fmaxf(sf[f][2][r], sf[f][3][r]));
            #pragma unroll
            for (int off = 1; off < 16; off <<= 1)
              v = fmaxf(v, __shfl_xor(v, off, 16));
            float mn = fmaxf(mrow[f][r], v);
            alpha[r] = __expf(mrow[f][r] - mn);
            mrow[f][r] = mn;
          }
          // P = exp(S-m) -> Ps (swizzled, conflict-free)
          #pragma unroll
          for (int nt = 0; nt < 4; nt++)
            #pragma unroll
            for (int r = 0; r < 4; r++) {
              float pv = __expf(sf[f][nt][r] - mrow[f][r]);
              Ps[w][(f * 16 + quad * 4 + r) * 72 + ((nt * 16 + ln) ^ (quad << 4))] = __float2bfloat16(pv);
            }
          #pragma unroll
          for (int dt = 0; dt < 4; dt++)
            #pragma unroll
            for (int r = 0; r < 4; r++)
              Oacc[f][dt][r] *= alpha[r];
          #pragma unroll
          for (int r = 0; r < 4; r++) lrow[f][r] *= alpha[r];
        }
        // PV (16 MFMAs) + row-sum via P*ones (4 MFMAs)
        #pragma unroll
        for (int f = 0; f < 2; f++) {
          f32x4 ls = {};
          #pragma unroll
          for (int kt = 0; kt < 2; kt++) {
            bf16x8 pf = *(const bf16x8*)&Ps[w][(f * 16 + ln) * 72 + ((kt * 32 + quad * 8) ^ psw)];
            ls = __builtin_amdgcn_mfma_f32_16x16x32_bf16(pf, ones, ls, 0, 0, 0);
            #pragma unroll
            for (int dt = 0; dt < 4; dt++) {
              bf16x8 vf = *(const bf16x8*)&Vs[(dt * 16 + ln) * 72 + ((kt * 32 + quad * 8) ^ (dt << 4))];
              Oacc[f][dt] = __builtin_amdgcn_mfma_f32_16x16x32_bf16(pf, vf, Oacc[f][dt], 0, 0, 0);
            }
          }
          #pragma unroll
          for (int r = 0; r < 4; r++) lrow[f][r] += ls[r];
        }
      }
      __syncthreads();
    }
    // epilogue
    #pragma unroll
    for (int f = 0; f < 2; f++) {
      const int so = qgw + f * 16 + quad * 4;
      #pragma unroll
      for (int dt = 0; dt < 4; dt++)
        #pragma unroll
        for (int r = 0; r < 4; r++)
          O[((size_t)(b * SEQ) + so + r) * DIM + h * HD + dt * 16 + ln] =
              __float2bfloat16(Oacc[f][dt][r] / lrow[f][r]);
    }
  }
}

extern "C" void kernel_launch(void* const* d_in, const int* in_sizes, int n_in,
                              void* d_out, int out_size, void* d_ws, size_t ws_size,
                              hipStream_t stream) {
  const float* x     = (const float*)d_in[0];
  const float* freqs = (const float*)d_in[1];
  const float* wqkv  = (const float*)d_in[2];
  const float* wo    = (const float*)d_in[3];
  float* out = (float*)d_out;

  char* ws = (char*)d_ws;
  __hip_bfloat16* xb    = (__hip_bfloat16*)ws; ws += (size_t)MTOT * DIM * 2;
  __hip_bfloat16* wqkvT = (__hip_bfloat16*)ws; ws += (size_t)QKV_N * DIM * 2;
  __hip_bfloat16* woT   = (__hip_bfloat16*)ws; ws += (size_t)DIM * DIM * 2;
  __hip_bfloat16* qkvb  = (__hip_bfloat16*)ws; ws += (size_t)MTOT * QKV_N * 2;
  __hip_bfloat16* Qb    = (__hip_bfloat16*)ws; ws += (size_t)BATCH * NH * SEQ * HD * 2;
  __hip_bfloat16* Kb    = (__hip_bfloat16*)ws; ws += (size_t)BATCH * NKV * SEQ * HD * 2;
  __hip_bfloat16* Vb    = (__hip_bfloat16*)ws; ws += (size_t)BATCH * NKV * SEQ * HD * 2;
  __hip_bfloat16* attn  = (__hip_bfloat16*)ws; ws += (size_t)MTOT * DIM * 2;

  cvt_x_kernel<<<(MTOT * DIM / 4 + 255) / 256, 256, 0, stream>>>(x, xb, MTOT * DIM / 4);
  transpose_cvt_kernel<<<dim3(QKV_N / 32, DIM / 32), 256, 0, stream>>>(wqkv, wqkvT, DIM, QKV_N);
  transpose_cvt_kernel<<<dim3(DIM / 32, DIM / 32), 256, 0, stream>>>(wo, woT, DIM, DIM);
  gemm_bt_kernel<__hip_bfloat16><<<dim3(QKV_N / 128, MTOT / 128), 256, 0, stream>>>(
      xb, wqkvT, qkvb, MTOT, QKV_N, DIM);
  rope_scatter_kernel<<<dim3(6, MTOT), 256, 0, stream>>>(qkvb, freqs, Qb, Kb, Vb);
  attn_kernel<<<dim3(8, NH, BATCH), 256, 0, stream>>>(Qb, Kb, Vb, attn);
  gemm_bt_kernel<float><<<dim3(DIM / 128, MTOT / 128), 256, 0, stream>>>(
      attn, woT, out, MTOT, DIM, DIM);
}